// Round 6
// baseline (175.567 us; speedup 1.0000x reference)
//
#include <hip/hip_runtime.h>
#include <hip/hip_bf16.h>

// GraphNet2: N=50000 nodes, E=1.6M edges, F=128.
// R1: global atomic scatter 91us (32B/op write-through) -> LDS privatization.
// R2: 128-block scatter, occupancy 9% -> split ranges across blocks.
// R3: k1 k-split spilled (VGPR=32, scratch round-trips) -> 79us.
// R4: k1 j-split (no spill) -> 160us; top-5 = harness 256MiB poison fills.
// R5: k2@1024thr/100KB regressed; k34 replica reduce latency-bound (44us,
//     403 GB/s): row-major rep means each block's 32KB working set strides
//     200KB apart.
// R6: transpose replica -> rep2[chunk][slice][64] (chunk=node/64): k2 writes
//     strided 256B bursts (stores don't stall), k34 reads one contiguous
//     32KB block -> streaming. k2 reverted to 512blk x 512thr x 64KB static.

#define NF 128
#define DENC 32
#define DEMB 12
#define DH 128

#define NSLICE 128       // replica rows (edge slices)
#define NRANGE 4         // node ranges
#define R_SCAT 16000     // LDS table entries (64000 B static)
#define ROWB (NSLICE*64) // floats per node-chunk in rep2 (8192)

// GEMV over one node row: acc[j] += x[k] * W[k*LDW + jbase + j], k=0..127.
// jbase is wave-uniform -> W/bias loads are s_loads. Also returns x[127].
template <int NJ, int LDW>
__device__ __forceinline__ void gemv_rows(
    const float4* __restrict__ x4p, const float* __restrict__ W,
    int jbase, const float* __restrict__ bias, float* acc, float& x_last)
{
#pragma unroll
    for (int j = 0; j < NJ; j++) acc[j] = bias[jbase + j];
#pragma unroll 2
    for (int c = 0; c < 8; c++) {
        float4 xa = x4p[4 * c + 0];
        float4 xb = x4p[4 * c + 1];
        float4 xc = x4p[4 * c + 2];
        float4 xd = x4p[4 * c + 3];
        float xs[16] = {xa.x, xa.y, xa.z, xa.w, xb.x, xb.y, xb.z, xb.w,
                        xc.x, xc.y, xc.z, xc.w, xd.x, xd.y, xd.z, xd.w};
#pragma unroll
        for (int u = 0; u < 16; u++) {
            const int k = 16 * c + u;
#pragma unroll
            for (int j = 0; j < NJ; j++)
                acc[j] = fmaf(xs[u], W[k * LDW + jbase + j], acc[j]);
        }
        if (c == 7) x_last = xd.w;
    }
}

// ---------------- K1: per-node encode, 4-way j-split ----------------------
__global__ __launch_bounds__(256) void k1_node(
    const float* __restrict__ nodes,
    const float* __restrict__ W_enc, const float* __restrict__ b_enc,
    const float* __restrict__ W_inf, const float* __restrict__ b_inf,
    const float* __restrict__ W_emb, const float* __restrict__ b_emb,
    float* __restrict__ p, float* __restrict__ inflb, float* __restrict__ embT,
    unsigned* __restrict__ cnt, int n_nodes)
{
    __shared__ float tabp[3][64];
    const int tid  = threadIdx.x;
    const int lane = tid & 63;
    const int wv   = __builtin_amdgcn_readfirstlane(tid >> 6);  // 0..3
    const int node = blockIdx.x * 64 + lane;
    const bool ok  = (node < n_nodes);

    if (blockIdx.x == 0 && tid == 0) *cnt = 0u;  // for k34 last-block pattern

    const float4* x4p = ok ? (const float4*)(nodes + (size_t)node * NF)
                           : (const float4*)nodes;

    float x127 = 0.f;
    if (wv == 3) {
        float acc[DEMB];
        gemv_rows<DEMB, DEMB>(x4p, W_emb, 0, b_emb, acc, x127);
        if (ok) {
#pragma unroll
            for (int j = 0; j < DEMB; j++)
                embT[(size_t)j * n_nodes + node] = acc[j];
        }
    } else {
        const int jbase = __builtin_amdgcn_readfirstlane(wv * 11);
        float pp = 0.f;
        if (wv == 2) {
            float acc[10];
            gemv_rows<10, DENC>(x4p, W_enc, jbase, b_enc, acc, x127);
#pragma unroll
            for (int j = 0; j < 10; j++)
                pp += fmaxf(acc[j], 0.f) * W_inf[jbase + j];
        } else {
            float acc[11];
            gemv_rows<11, DENC>(x4p, W_enc, jbase, b_enc, acc, x127);
#pragma unroll
            for (int j = 0; j < 11; j++)
                pp += fmaxf(acc[j], 0.f) * W_inf[jbase + j];
        }
        tabp[wv][lane] = pp;
    }
    __syncthreads();

    if (wv == 0 && ok) {
        float pn = tabp[0][lane] + tabp[1][lane] + tabp[2][lane];
        p[node] = pn;
        inflb[node] = pn + x127 * W_inf[DENC] + b_inf[0];
    }
}

// ---------------- K2: LDS scatter -> transposed replica -------------------
// grid = NSLICE*NRANGE blocks; block (slice, rng) owns nodes
// [rng*16000, rng*16000+rng) of edge slice `slice`. Output layout:
// rep2[chunk][slice][col], chunk=node/64, col=node%64. 16000%64==0 so each
// chunk is written by exactly one (slice,rng) block.
__global__ __launch_bounds__(512) void k2_scatter(
    const int* __restrict__ senders, const int* __restrict__ recvs,
    const float* __restrict__ p, float* __restrict__ rep2,
    int n_nodes, int n_edges)
{
    __shared__ float tab[R_SCAT];
    const int slice = blockIdx.x >> 2;       // edge slice (0..127)
    const int rng_i = blockIdx.x & 3;        // node range (0..3)
    const int e0 = (int)((long long)n_edges * slice / NSLICE);
    const int e1 = (int)((long long)n_edges * (slice + 1) / NSLICE);
    const int lo = rng_i * R_SCAT;
    const int rng = min(R_SCAT, n_nodes - lo);

    float4* tab4 = (float4*)tab;
    for (int i = threadIdx.x; i < (rng + 3) / 4; i += 512)
        tab4[i] = make_float4(0.f, 0.f, 0.f, 0.f);
    __syncthreads();

    // aligned int4 main loop + scalar tails (E/NSLICE=12500, %4==0 -> no-op)
    const int ae0 = (e0 + 3) & ~3;
    const int ae1 = e1 & ~3;
    for (int e = e0 + (int)threadIdx.x; e < ae0; e += 512) {
        unsigned rr = (unsigned)(recvs[e] - lo);
        if (rr < (unsigned)rng) atomicAdd(&tab[rr], p[senders[e]]);
    }
    const int4* r4 = (const int4*)recvs;
    const int4* s4 = (const int4*)senders;
    for (int i = ae0 / 4 + (int)threadIdx.x; i < ae1 / 4; i += 512) {
        int4 r = r4[i];
        int4 s = s4[i];
        unsigned rr;
        rr = (unsigned)(r.x - lo); if (rr < (unsigned)rng) atomicAdd(&tab[rr], p[s.x]);
        rr = (unsigned)(r.y - lo); if (rr < (unsigned)rng) atomicAdd(&tab[rr], p[s.y]);
        rr = (unsigned)(r.z - lo); if (rr < (unsigned)rng) atomicAdd(&tab[rr], p[s.z]);
        rr = (unsigned)(r.w - lo); if (rr < (unsigned)rng) atomicAdd(&tab[rr], p[s.w]);
    }
    for (int e = ae1 + (int)threadIdx.x; e < e1; e += 512) {
        unsigned rr = (unsigned)(recvs[e] - lo);
        if (rr < (unsigned)rng) atomicAdd(&tab[rr], p[senders[e]]);
    }
    __syncthreads();

    // writeback: local idx i -> chunk=i/64, col=i%64 (lo%64==0)
    float4* dst4 = (float4*)(rep2 + (size_t)(lo >> 6) * ROWB + slice * 64);
    for (int i4 = threadIdx.x; i4 < rng / 4; i4 += 512) {
        const int chunk = i4 >> 4;            // i/64
        const int col4  = i4 & 15;            // (i%64)/4
        dst4[(size_t)chunk * (ROWB / 4) + col4] = tab4[i4];
    }
    for (int i = (rng & ~3) + threadIdx.x; i < rng; i += 512)
        rep2[(size_t)(lo >> 6) * ROWB + (size_t)(i >> 6) * ROWB
             + slice * 64 + (i & 63)] = tab[i];
}

// ---------------- K34: streaming replica reduce + softmax + head ----------
__global__ __launch_bounds__(256) void k34_soft(
    const float* __restrict__ inflb, const float* __restrict__ rep2,
    const float* __restrict__ embT, float* __restrict__ psum,
    unsigned* __restrict__ cnt,
    const float* __restrict__ W1, const float* __restrict__ b1,
    const float* __restrict__ W2, const float* __restrict__ b2,
    const float* __restrict__ Wy, const float* __restrict__ by,
    const float* __restrict__ Wx, const float* __restrict__ bx,
    float* __restrict__ out, int n_nodes, int nblk)
{
    __shared__ float tab[4][64];
    const int tid  = threadIdx.x;
    const int lane = tid & 63;
    const int wv   = __builtin_amdgcn_readfirstlane(tid >> 6);
    const int node = blockIdx.x * 64 + lane;
    const bool ok  = (node < n_nodes);

    // ---- phase A: reduce 128 replica rows from a contiguous 32 KB block --
    {
        const float* base = rep2 + (size_t)blockIdx.x * ROWB + 32 * wv * 64 + lane;
        float s = 0.f;
#pragma unroll 8
        for (int i = 0; i < 32; i++)
            s += base[i * 64];
        tab[wv][lane] = ok ? s : 0.f;
    }
    __syncthreads();

    // ---- phase B: block softmax partial (wave 0) ----
    if (wv == 0) {
        float infl = ok ? inflb[node] + tab[0][lane] + tab[1][lane]
                          + tab[2][lane] + tab[3][lane]
                        : -1e30f;
        float m = infl;
#pragma unroll
        for (int off = 32; off; off >>= 1)
            m = fmaxf(m, __shfl_down(m, off, 64));
        m = __shfl(m, 0, 64);

        const float w = ok ? expf(infl - m) : 0.f;
        float v13[13];
        v13[0] = w;
#pragma unroll
        for (int j = 0; j < DEMB; j++)
            v13[1 + j] = ok ? w * embT[(size_t)j * n_nodes + node] : 0.f;

#pragma unroll
        for (int v = 0; v < 13; v++) {
            float x = v13[v];
#pragma unroll
            for (int off = 32; off; off >>= 1)
                x += __shfl_down(x, off, 64);
            v13[v] = x;
        }
        if (lane == 0) {
            psum[blockIdx.x * 14] = m;
#pragma unroll
            for (int v = 0; v < 13; v++)
                psum[blockIdx.x * 14 + 1 + v] = v13[v];
        }
    }
    __syncthreads();

    // ---- phase C: last block merges all partials + runs the MLP head ----
    __shared__ int is_last;
    if (tid == 0) {
        __threadfence();                       // release psum row
        unsigned old = atomicAdd(cnt, 1u);
        is_last = (old == (unsigned)(nblk - 1)) ? 1 : 0;
    }
    __syncthreads();
    if (!is_last) return;
    __threadfence();                           // acquire all psum rows

    const int w4 = tid >> 6, l4 = tid & 63;

    float m = -1e30f;
    for (int b = tid; b < nblk; b += 256) m = fmaxf(m, psum[b * 14]);
#pragma unroll
    for (int off = 32; off; off >>= 1)
        m = fmaxf(m, __shfl_down(m, off, 64));
    __shared__ float smx[4];
    __shared__ float sM;
    if (l4 == 0) smx[w4] = m;
    __syncthreads();
    if (tid == 0)
        sM = fmaxf(fmaxf(smx[0], smx[1]), fmaxf(smx[2], smx[3]));
    __syncthreads();
    const float M = sM;

    float acc[13];
#pragma unroll
    for (int v = 0; v < 13; v++) acc[v] = 0.f;
    for (int b = tid; b < nblk; b += 256) {
        float sc = expf(psum[b * 14] - M);
#pragma unroll
        for (int v = 0; v < 13; v++)
            acc[v] = fmaf(sc, psum[b * 14 + 1 + v], acc[v]);
    }

    __shared__ float red[4][13];
#pragma unroll
    for (int v = 0; v < 13; v++) {
        float xx = acc[v];
#pragma unroll
        for (int off = 32; off; off >>= 1)
            xx += __shfl_down(xx, off, 64);
        if (l4 == 0) red[w4][v] = xx;
    }
    __syncthreads();

    __shared__ float g[DEMB];
    __shared__ float h1[DH];
    __shared__ float h2[DH];
    if (tid < DEMB) {
        float S = red[0][0] + red[1][0] + red[2][0] + red[3][0];
        g[tid] = (red[0][1 + tid] + red[1][1 + tid] +
                  red[2][1 + tid] + red[3][1 + tid]) / S;
    }
    __syncthreads();

    if (tid < DH) {
        float s1 = b1[tid];
#pragma unroll
        for (int i = 0; i < DEMB; i++) s1 = fmaf(g[i], W1[i * DH + tid], s1);
        h1[tid] = fmaxf(s1, 0.f);
    }
    __syncthreads();

    if (tid < DH) {
        float s2v = b2[tid];
        for (int i = 0; i < DH; i++) s2v = fmaf(h1[i], W2[i * DH + tid], s2v);
        h2[tid] = fmaxf(s2v, 0.f);
    }
    __syncthreads();

    if (tid < 4) {
        float lg = bx[tid];
        for (int i = 0; i < DH; i++) lg = fmaf(h2[i], Wx[i * 4 + tid], lg);
        out[tid] = lg / 10.0f;
    } else if (tid == 4) {
        float v = by[0];
        for (int i = 0; i < DH; i++) v = fmaf(h2[i], Wy[i], v);
        out[4] = v;
    }
}

extern "C" void kernel_launch(void* const* d_in, const int* in_sizes, int n_in,
                              void* d_out, int out_size, void* d_ws, size_t ws_size,
                              hipStream_t stream) {
    const float* nodes   = (const float*)d_in[0];
    const int*   senders = (const int*)d_in[1];
    const int*   recvs   = (const int*)d_in[2];
    const float* W_enc   = (const float*)d_in[3];
    const float* b_enc   = (const float*)d_in[4];
    const float* W_inf   = (const float*)d_in[5];
    const float* b_inf   = (const float*)d_in[6];
    const float* W_emb   = (const float*)d_in[7];
    const float* b_emb   = (const float*)d_in[8];
    const float* W1      = (const float*)d_in[9];
    const float* b1      = (const float*)d_in[10];
    const float* W2      = (const float*)d_in[11];
    const float* b2      = (const float*)d_in[12];
    const float* Wy      = (const float*)d_in[13];
    const float* by      = (const float*)d_in[14];
    const float* Wx      = (const float*)d_in[15];
    const float* bx      = (const float*)d_in[16];
    float* out = (float*)d_out;

    const int n_nodes = in_sizes[0] / NF;   // 50000
    const int n_edges = in_sizes[1];        // 1600000
    const int nb64 = (n_nodes + 63) / 64;   // 782

    // workspace layout (floats):
    float* ws    = (float*)d_ws;
    float* p     = ws;                                    // [N]
    float* inflb = ws + n_nodes;                          // [N]
    float* embT  = ws + 2 * (size_t)n_nodes;              // [12][N]
    float* rep2  = ws + 14 * (size_t)n_nodes;             // [nb64][128][64]
    float* psum  = rep2 + (size_t)nb64 * ROWB;            // [nb64*14]
    unsigned* cnt = (unsigned*)(psum + (size_t)nb64 * 14 + 4);

    hipLaunchKernelGGL(k1_node, dim3(nb64), dim3(256), 0, stream,
                       nodes, W_enc, b_enc, W_inf, b_inf, W_emb, b_emb,
                       p, inflb, embT, cnt, n_nodes);
    hipLaunchKernelGGL(k2_scatter, dim3(NSLICE * NRANGE), dim3(512), 0, stream,
                       senders, recvs, p, rep2, n_nodes, n_edges);
    hipLaunchKernelGGL(k34_soft, dim3(nb64), dim3(256), 0, stream,
                       inflb, rep2, embT, psum, cnt,
                       W1, b1, W2, b2, Wy, by, Wx, bx, out, n_nodes, nb64);
}

// Round 7
// 155.902 us; speedup vs baseline: 1.1261x; 1.1261x over previous
//
#include <hip/hip_runtime.h>
#include <hip/hip_bf16.h>

// GraphNet2: N=50000 nodes, E=1.6M edges, F=128.
// R1: global atomic scatter 91us (32B/op write-through) -> LDS privatization.
// R2: 128-block scatter, occupancy 9% -> split ranges across blocks.
// R3: k1 k-split spilled (VGPR=32, scratch round-trips) -> 79us.
// R4: k1 j-split (no spill) -> 160us; top-5 = harness 256MiB poison fills.
// R5/R6: k3+k4 fusion REGRESSED (+15us): compiler sized k34 at VGPR=24 for
//     the high-occupancy phases -> phase C acc[13] spilled, and the 1-block
//     head tail (4 waves, no latency hiding) ran inside the dispatch.
//     rep2 transpose was neutral -> phase A never was the bottleneck.
// R7: un-fuse. k3 = phases A+B only. New k4_head: 512 thr, launch_bounds
//     (512,1) for registers, 4-way k-split on the 128x128 layer (32 loads/
//     thread vs 128 serial), shfl-reduced output heads.

#define NF 128
#define DENC 32
#define DEMB 12
#define DH 128

#define NSLICE 128       // replica rows (edge slices)
#define NRANGE 4         // node ranges
#define R_SCAT 16000     // LDS table entries (64000 B static)
#define ROWB (NSLICE*64) // floats per node-chunk in rep2 (8192)

// GEMV over one node row: acc[j] += x[k] * W[k*LDW + jbase + j], k=0..127.
// jbase is wave-uniform -> W/bias loads are s_loads. Also returns x[127].
template <int NJ, int LDW>
__device__ __forceinline__ void gemv_rows(
    const float4* __restrict__ x4p, const float* __restrict__ W,
    int jbase, const float* __restrict__ bias, float* acc, float& x_last)
{
#pragma unroll
    for (int j = 0; j < NJ; j++) acc[j] = bias[jbase + j];
#pragma unroll 2
    for (int c = 0; c < 8; c++) {
        float4 xa = x4p[4 * c + 0];
        float4 xb = x4p[4 * c + 1];
        float4 xc = x4p[4 * c + 2];
        float4 xd = x4p[4 * c + 3];
        float xs[16] = {xa.x, xa.y, xa.z, xa.w, xb.x, xb.y, xb.z, xb.w,
                        xc.x, xc.y, xc.z, xc.w, xd.x, xd.y, xd.z, xd.w};
#pragma unroll
        for (int u = 0; u < 16; u++) {
            const int k = 16 * c + u;
#pragma unroll
            for (int j = 0; j < NJ; j++)
                acc[j] = fmaf(xs[u], W[k * LDW + jbase + j], acc[j]);
        }
        if (c == 7) x_last = xd.w;
    }
}

// ---------------- K1: per-node encode, 4-way j-split ----------------------
__global__ __launch_bounds__(256) void k1_node(
    const float* __restrict__ nodes,
    const float* __restrict__ W_enc, const float* __restrict__ b_enc,
    const float* __restrict__ W_inf, const float* __restrict__ b_inf,
    const float* __restrict__ W_emb, const float* __restrict__ b_emb,
    float* __restrict__ p, float* __restrict__ inflb, float* __restrict__ embT,
    int n_nodes)
{
    __shared__ float tabp[3][64];
    const int tid  = threadIdx.x;
    const int lane = tid & 63;
    const int wv   = __builtin_amdgcn_readfirstlane(tid >> 6);  // 0..3
    const int node = blockIdx.x * 64 + lane;
    const bool ok  = (node < n_nodes);

    const float4* x4p = ok ? (const float4*)(nodes + (size_t)node * NF)
                           : (const float4*)nodes;

    float x127 = 0.f;
    if (wv == 3) {
        float acc[DEMB];
        gemv_rows<DEMB, DEMB>(x4p, W_emb, 0, b_emb, acc, x127);
        if (ok) {
#pragma unroll
            for (int j = 0; j < DEMB; j++)
                embT[(size_t)j * n_nodes + node] = acc[j];
        }
    } else {
        const int jbase = __builtin_amdgcn_readfirstlane(wv * 11);
        float pp = 0.f;
        if (wv == 2) {
            float acc[10];
            gemv_rows<10, DENC>(x4p, W_enc, jbase, b_enc, acc, x127);
#pragma unroll
            for (int j = 0; j < 10; j++)
                pp += fmaxf(acc[j], 0.f) * W_inf[jbase + j];
        } else {
            float acc[11];
            gemv_rows<11, DENC>(x4p, W_enc, jbase, b_enc, acc, x127);
#pragma unroll
            for (int j = 0; j < 11; j++)
                pp += fmaxf(acc[j], 0.f) * W_inf[jbase + j];
        }
        tabp[wv][lane] = pp;
    }
    __syncthreads();

    if (wv == 0 && ok) {
        float pn = tabp[0][lane] + tabp[1][lane] + tabp[2][lane];
        p[node] = pn;
        inflb[node] = pn + x127 * W_inf[DENC] + b_inf[0];
    }
}

// ---------------- K2: LDS scatter -> transposed replica -------------------
__global__ __launch_bounds__(512) void k2_scatter(
    const int* __restrict__ senders, const int* __restrict__ recvs,
    const float* __restrict__ p, float* __restrict__ rep2,
    int n_nodes, int n_edges)
{
    __shared__ float tab[R_SCAT];
    const int slice = blockIdx.x >> 2;       // edge slice (0..127)
    const int rng_i = blockIdx.x & 3;        // node range (0..3)
    const int e0 = (int)((long long)n_edges * slice / NSLICE);
    const int e1 = (int)((long long)n_edges * (slice + 1) / NSLICE);
    const int lo = rng_i * R_SCAT;
    const int rng = min(R_SCAT, n_nodes - lo);

    float4* tab4 = (float4*)tab;
    for (int i = threadIdx.x; i < (rng + 3) / 4; i += 512)
        tab4[i] = make_float4(0.f, 0.f, 0.f, 0.f);
    __syncthreads();

    const int ae0 = (e0 + 3) & ~3;
    const int ae1 = e1 & ~3;
    for (int e = e0 + (int)threadIdx.x; e < ae0; e += 512) {
        unsigned rr = (unsigned)(recvs[e] - lo);
        if (rr < (unsigned)rng) atomicAdd(&tab[rr], p[senders[e]]);
    }
    const int4* r4 = (const int4*)recvs;
    const int4* s4 = (const int4*)senders;
    for (int i = ae0 / 4 + (int)threadIdx.x; i < ae1 / 4; i += 512) {
        int4 r = r4[i];
        int4 s = s4[i];
        unsigned rr;
        rr = (unsigned)(r.x - lo); if (rr < (unsigned)rng) atomicAdd(&tab[rr], p[s.x]);
        rr = (unsigned)(r.y - lo); if (rr < (unsigned)rng) atomicAdd(&tab[rr], p[s.y]);
        rr = (unsigned)(r.z - lo); if (rr < (unsigned)rng) atomicAdd(&tab[rr], p[s.z]);
        rr = (unsigned)(r.w - lo); if (rr < (unsigned)rng) atomicAdd(&tab[rr], p[s.w]);
    }
    for (int e = ae1 + (int)threadIdx.x; e < e1; e += 512) {
        unsigned rr = (unsigned)(recvs[e] - lo);
        if (rr < (unsigned)rng) atomicAdd(&tab[rr], p[senders[e]]);
    }
    __syncthreads();

    // writeback: local idx i -> chunk=i/64, col=i%64 (lo%64==0)
    float4* dst4 = (float4*)(rep2 + (size_t)(lo >> 6) * ROWB + slice * 64);
    for (int i4 = threadIdx.x; i4 < rng / 4; i4 += 512) {
        const int chunk = i4 >> 4;
        const int col4  = i4 & 15;
        dst4[(size_t)chunk * (ROWB / 4) + col4] = tab4[i4];
    }
    for (int i = (rng & ~3) + threadIdx.x; i < rng; i += 512)
        rep2[(size_t)(lo >> 6) * ROWB + (size_t)(i >> 6) * ROWB
             + slice * 64 + (i & 63)] = tab[i];
}

// ---------------- K3: streaming replica reduce + softmax partials ---------
__global__ __launch_bounds__(256) void k3_soft(
    const float* __restrict__ inflb, const float* __restrict__ rep2,
    const float* __restrict__ embT, float* __restrict__ psum, int n_nodes)
{
    __shared__ float tab[4][64];
    const int tid  = threadIdx.x;
    const int lane = tid & 63;
    const int wv   = __builtin_amdgcn_readfirstlane(tid >> 6);
    const int node = blockIdx.x * 64 + lane;
    const bool ok  = (node < n_nodes);

    // phase A: reduce 128 replica rows from a contiguous 32 KB block
    {
        const float* base = rep2 + (size_t)blockIdx.x * ROWB + 32 * wv * 64 + lane;
        float s = 0.f;
#pragma unroll 8
        for (int i = 0; i < 32; i++)
            s += base[i * 64];
        tab[wv][lane] = ok ? s : 0.f;
    }
    __syncthreads();

    // phase B: block softmax partial (wave 0)
    if (wv == 0) {
        float infl = ok ? inflb[node] + tab[0][lane] + tab[1][lane]
                          + tab[2][lane] + tab[3][lane]
                        : -1e30f;
        float m = infl;
#pragma unroll
        for (int off = 32; off; off >>= 1)
            m = fmaxf(m, __shfl_down(m, off, 64));
        m = __shfl(m, 0, 64);

        const float w = ok ? expf(infl - m) : 0.f;
        float v13[13];
        v13[0] = w;
#pragma unroll
        for (int j = 0; j < DEMB; j++)
            v13[1 + j] = ok ? w * embT[(size_t)j * n_nodes + node] : 0.f;

#pragma unroll
        for (int v = 0; v < 13; v++) {
            float x = v13[v];
#pragma unroll
            for (int off = 32; off; off >>= 1)
                x += __shfl_down(x, off, 64);
            v13[v] = x;
        }
        if (lane == 0) {
            psum[blockIdx.x * 14] = m;
#pragma unroll
            for (int v = 0; v < 13; v++)
                psum[blockIdx.x * 14 + 1 + v] = v13[v];
        }
    }
}

// ---------------- K4: merge partials + MLP head (512 thr, reg-rich) -------
__global__ __launch_bounds__(512, 1) void k4_head(
    const float* __restrict__ psum,
    const float* __restrict__ W1, const float* __restrict__ b1,
    const float* __restrict__ W2, const float* __restrict__ b2,
    const float* __restrict__ Wy, const float* __restrict__ by,
    const float* __restrict__ Wx, const float* __restrict__ bx,
    float* __restrict__ out, int nblk)
{
    const int t  = threadIdx.x;
    const int wv = t >> 6;      // 0..7
    const int ln = t & 63;

    __shared__ float sred[8][14];
    __shared__ float tot[14];
    __shared__ float g[DEMB];
    __shared__ float h1[DH];
    __shared__ float part[4][DH];
    __shared__ float h2[DH];
    __shared__ float wred[8][5];

    // --- global max over per-block maxima (2 strided iters / thread) ---
    float m = -1e30f;
    for (int b = t; b < nblk; b += 512) m = fmaxf(m, psum[b * 14]);
#pragma unroll
    for (int off = 32; off; off >>= 1)
        m = fmaxf(m, __shfl_down(m, off, 64));
    if (ln == 0) sred[wv][0] = m;
    __syncthreads();
    float M = sred[0][0];
#pragma unroll
    for (int i = 1; i < 8; i++) M = fmaxf(M, sred[i][0]);
    __syncthreads();

    // --- exp-scaled 13-vector partial sums ---
    float acc[13];
#pragma unroll
    for (int v = 0; v < 13; v++) acc[v] = 0.f;
    for (int b = t; b < nblk; b += 512) {
        float sc = expf(psum[b * 14] - M);
#pragma unroll
        for (int v = 0; v < 13; v++)
            acc[v] = fmaf(sc, psum[b * 14 + 1 + v], acc[v]);
    }
#pragma unroll
    for (int v = 0; v < 13; v++) {
        float x = acc[v];
#pragma unroll
        for (int off = 32; off; off >>= 1)
            x += __shfl_down(x, off, 64);
        if (ln == 0) sred[wv][v] = x;
    }
    __syncthreads();
    if (t < 13) {
        float s = 0.f;
#pragma unroll
        for (int i = 0; i < 8; i++) s += sred[i][t];
        tot[t] = s;
    }
    __syncthreads();
    if (t < DEMB) g[t] = tot[1 + t] / tot[0];
    __syncthreads();

    // --- h1 = relu(g @ W1 + b1), W1 [12,128] ---
    if (t < DH) {
        float s1 = b1[t];
#pragma unroll
        for (int i = 0; i < DEMB; i++) s1 = fmaf(g[i], W1[i * DH + t], s1);
        h1[t] = fmaxf(s1, 0.f);
    }
    __syncthreads();

    // --- h2 = relu(h1 @ W2 + b2), W2 [128,128], 4-way k-split ---
    {
        const int o  = t & 127;
        const int ks = t >> 7;           // 0..3
        float s = 0.f;
        const float* w2 = W2 + (size_t)(32 * ks) * DH + o;
#pragma unroll 8
        for (int i = 0; i < 32; i++)
            s = fmaf(h1[32 * ks + i], w2[i * DH], s);
        part[ks][o] = s;
    }
    __syncthreads();
    if (t < DH)
        h2[t] = fmaxf(b2[t] + part[0][t] + part[1][t] + part[2][t] + part[3][t], 0.f);
    __syncthreads();

    // --- heads: logits = h2 @ Wx (4), value = h2 @ Wy (1) ---
    if (t < DH) {
        const float v = h2[t];
        float pr[5];
#pragma unroll
        for (int j = 0; j < 4; j++) pr[j] = v * Wx[t * 4 + j];
        pr[4] = v * Wy[t];
#pragma unroll
        for (int j = 0; j < 5; j++) {
            float x = pr[j];
#pragma unroll
            for (int off = 32; off; off >>= 1)
                x += __shfl_down(x, off, 64);
            if (ln == 0) wred[wv][j] = x;
        }
    }
    __syncthreads();
    if (t < 4)
        out[t] = (wred[0][t] + wred[1][t] + bx[t]) / 10.0f;
    else if (t == 4)
        out[4] = wred[0][4] + wred[1][4] + by[0];
}

extern "C" void kernel_launch(void* const* d_in, const int* in_sizes, int n_in,
                              void* d_out, int out_size, void* d_ws, size_t ws_size,
                              hipStream_t stream) {
    const float* nodes   = (const float*)d_in[0];
    const int*   senders = (const int*)d_in[1];
    const int*   recvs   = (const int*)d_in[2];
    const float* W_enc   = (const float*)d_in[3];
    const float* b_enc   = (const float*)d_in[4];
    const float* W_inf   = (const float*)d_in[5];
    const float* b_inf   = (const float*)d_in[6];
    const float* W_emb   = (const float*)d_in[7];
    const float* b_emb   = (const float*)d_in[8];
    const float* W1      = (const float*)d_in[9];
    const float* b1      = (const float*)d_in[10];
    const float* W2      = (const float*)d_in[11];
    const float* b2      = (const float*)d_in[12];
    const float* Wy      = (const float*)d_in[13];
    const float* by      = (const float*)d_in[14];
    const float* Wx      = (const float*)d_in[15];
    const float* bx      = (const float*)d_in[16];
    float* out = (float*)d_out;

    const int n_nodes = in_sizes[0] / NF;   // 50000
    const int n_edges = in_sizes[1];        // 1600000
    const int nb64 = (n_nodes + 63) / 64;   // 782

    // workspace layout (floats):
    float* ws    = (float*)d_ws;
    float* p     = ws;                                    // [N]
    float* inflb = ws + n_nodes;                          // [N]
    float* embT  = ws + 2 * (size_t)n_nodes;              // [12][N]
    float* rep2  = ws + 14 * (size_t)n_nodes;             // [nb64][128][64]
    float* psum  = rep2 + (size_t)nb64 * ROWB;            // [nb64*14]

    hipLaunchKernelGGL(k1_node, dim3(nb64), dim3(256), 0, stream,
                       nodes, W_enc, b_enc, W_inf, b_inf, W_emb, b_emb,
                       p, inflb, embT, n_nodes);
    hipLaunchKernelGGL(k2_scatter, dim3(NSLICE * NRANGE), dim3(512), 0, stream,
                       senders, recvs, p, rep2, n_nodes, n_edges);
    hipLaunchKernelGGL(k3_soft, dim3(nb64), dim3(256), 0, stream,
                       inflb, rep2, embT, psum, n_nodes);
    hipLaunchKernelGGL(k4_head, dim3(1), dim3(512), 0, stream,
                       psum, W1, b1, W2, b2, Wy, by, Wx, bx, out, nb64);
}

// Round 8
// 153.537 us; speedup vs baseline: 1.1435x; 1.0154x over previous
//
#include <hip/hip_runtime.h>
#include <hip/hip_bf16.h>

// GraphNet2: N=50000 nodes, E=1.6M edges, F=128.
// R1: global atomic scatter 91us (32B/op write-through) -> LDS privatization.
// R2: 128-block scatter, occupancy 9% -> split ranges across blocks.
// R3: k1 k-split spilled (VGPR=32, scratch round-trips) -> 79us.
// R4: k1 j-split (no spill) -> 160us; top-5 = harness 256MiB poison fills.
// R5/R6: k3+k4 fusion regressed +19us (phase-C spill @ VGPR=24 + 1-block
//     tail); rep2 transpose neutral. Delta algebra shows R5's k2 (1024thr,
//     100KB LDS, NRANGE=2) was ~5us FASTER - wrongly reverted in R6.
// R7: un-fused -> 156us. All compute kernels < 43.5us (below fill cutoff).
//     Fixed in-window harness overhead ~60-70us (poison fill + restores).
// R8: re-adopt 1024thr/100KB/NRANGE=2 k2 (halves edge rescans); k3 phase A
//     float4 (1KB/wave/inst, 8 iters vs 32) + xor-shfl slice reduction.

#define NF 128
#define DENC 32
#define DEMB 12
#define DH 128

#define NSLICE 128       // replica rows (edge slices)
#define NRANGE 2         // node ranges
#define R_SCAT 25024     // LDS table entries (100096 B dynamic), %64==0
#define ROWB (NSLICE*64) // floats per node-chunk in rep2 (8192)

// GEMV over one node row: acc[j] += x[k] * W[k*LDW + jbase + j], k=0..127.
// jbase is wave-uniform -> W/bias loads are s_loads. Also returns x[127].
template <int NJ, int LDW>
__device__ __forceinline__ void gemv_rows(
    const float4* __restrict__ x4p, const float* __restrict__ W,
    int jbase, const float* __restrict__ bias, float* acc, float& x_last)
{
#pragma unroll
    for (int j = 0; j < NJ; j++) acc[j] = bias[jbase + j];
#pragma unroll 2
    for (int c = 0; c < 8; c++) {
        float4 xa = x4p[4 * c + 0];
        float4 xb = x4p[4 * c + 1];
        float4 xc = x4p[4 * c + 2];
        float4 xd = x4p[4 * c + 3];
        float xs[16] = {xa.x, xa.y, xa.z, xa.w, xb.x, xb.y, xb.z, xb.w,
                        xc.x, xc.y, xc.z, xc.w, xd.x, xd.y, xd.z, xd.w};
#pragma unroll
        for (int u = 0; u < 16; u++) {
            const int k = 16 * c + u;
#pragma unroll
            for (int j = 0; j < NJ; j++)
                acc[j] = fmaf(xs[u], W[k * LDW + jbase + j], acc[j]);
        }
        if (c == 7) x_last = xd.w;
    }
}

// ---------------- K1: per-node encode, 4-way j-split ----------------------
__global__ __launch_bounds__(256) void k1_node(
    const float* __restrict__ nodes,
    const float* __restrict__ W_enc, const float* __restrict__ b_enc,
    const float* __restrict__ W_inf, const float* __restrict__ b_inf,
    const float* __restrict__ W_emb, const float* __restrict__ b_emb,
    float* __restrict__ p, float* __restrict__ inflb, float* __restrict__ embT,
    int n_nodes)
{
    __shared__ float tabp[3][64];
    const int tid  = threadIdx.x;
    const int lane = tid & 63;
    const int wv   = __builtin_amdgcn_readfirstlane(tid >> 6);  // 0..3
    const int node = blockIdx.x * 64 + lane;
    const bool ok  = (node < n_nodes);

    const float4* x4p = ok ? (const float4*)(nodes + (size_t)node * NF)
                           : (const float4*)nodes;

    float x127 = 0.f;
    if (wv == 3) {
        float acc[DEMB];
        gemv_rows<DEMB, DEMB>(x4p, W_emb, 0, b_emb, acc, x127);
        if (ok) {
#pragma unroll
            for (int j = 0; j < DEMB; j++)
                embT[(size_t)j * n_nodes + node] = acc[j];
        }
    } else {
        const int jbase = __builtin_amdgcn_readfirstlane(wv * 11);
        float pp = 0.f;
        if (wv == 2) {
            float acc[10];
            gemv_rows<10, DENC>(x4p, W_enc, jbase, b_enc, acc, x127);
#pragma unroll
            for (int j = 0; j < 10; j++)
                pp += fmaxf(acc[j], 0.f) * W_inf[jbase + j];
        } else {
            float acc[11];
            gemv_rows<11, DENC>(x4p, W_enc, jbase, b_enc, acc, x127);
#pragma unroll
            for (int j = 0; j < 11; j++)
                pp += fmaxf(acc[j], 0.f) * W_inf[jbase + j];
        }
        tabp[wv][lane] = pp;
    }
    __syncthreads();

    if (wv == 0 && ok) {
        float pn = tabp[0][lane] + tabp[1][lane] + tabp[2][lane];
        p[node] = pn;
        inflb[node] = pn + x127 * W_inf[DENC] + b_inf[0];
    }
}

// ---------------- K2: LDS scatter -> transposed replica -------------------
// 256 blocks = 128 edge-slices x 2 range-owners; 1024 thr; 100KB dynamic LDS.
__global__ __launch_bounds__(1024) void k2_scatter(
    const int* __restrict__ senders, const int* __restrict__ recvs,
    const float* __restrict__ p, float* __restrict__ rep2,
    int n_nodes, int n_edges)
{
    extern __shared__ float tab[];           // R_SCAT floats
    const int slice = blockIdx.x >> 1;       // edge slice (0..127)
    const int rng_i = blockIdx.x & 1;        // node range (0..1)
    const int e0 = (int)((long long)n_edges * slice / NSLICE);
    const int e1 = (int)((long long)n_edges * (slice + 1) / NSLICE);
    const int lo = rng_i * R_SCAT;
    const int rng = min(R_SCAT, n_nodes - lo);

    float4* tab4 = (float4*)tab;
    for (int i = threadIdx.x; i < (rng + 3) / 4; i += 1024)
        tab4[i] = make_float4(0.f, 0.f, 0.f, 0.f);
    __syncthreads();

    // aligned int4 main loop + scalar tails (E/NSLICE=12500 %4==0 -> empty)
    const int ae0 = (e0 + 3) & ~3;
    const int ae1 = e1 & ~3;
    for (int e = e0 + (int)threadIdx.x; e < ae0; e += 1024) {
        unsigned rr = (unsigned)(recvs[e] - lo);
        if (rr < (unsigned)rng) atomicAdd(&tab[rr], p[senders[e]]);
    }
    const int4* r4 = (const int4*)recvs;
    const int4* s4 = (const int4*)senders;
    for (int i = ae0 / 4 + (int)threadIdx.x; i < ae1 / 4; i += 1024) {
        int4 r = r4[i];
        int4 s = s4[i];
        unsigned rr;
        rr = (unsigned)(r.x - lo); if (rr < (unsigned)rng) atomicAdd(&tab[rr], p[s.x]);
        rr = (unsigned)(r.y - lo); if (rr < (unsigned)rng) atomicAdd(&tab[rr], p[s.y]);
        rr = (unsigned)(r.z - lo); if (rr < (unsigned)rng) atomicAdd(&tab[rr], p[s.z]);
        rr = (unsigned)(r.w - lo); if (rr < (unsigned)rng) atomicAdd(&tab[rr], p[s.w]);
    }
    for (int e = ae1 + (int)threadIdx.x; e < e1; e += 1024) {
        unsigned rr = (unsigned)(recvs[e] - lo);
        if (rr < (unsigned)rng) atomicAdd(&tab[rr], p[senders[e]]);
    }
    __syncthreads();

    // float4 writeback into rep2[chunk][slice][col]; lo%64==0, rng%4==0
    const int g4base = lo >> 2;
    for (int i4 = threadIdx.x; i4 < rng / 4; i4 += 1024) {
        const int g4    = g4base + i4;
        const int chunk = g4 >> 4;
        const int col4  = g4 & 15;
        ((float4*)rep2)[(size_t)chunk * (ROWB / 4) + slice * 16 + col4] = tab4[i4];
    }
    for (int i = (rng & ~3) + threadIdx.x; i < rng; i += 1024) {
        const int g = lo + i;
        rep2[(size_t)(g >> 6) * ROWB + slice * 64 + (g & 63)] = tab[i];
    }
}

// ---------------- K3: float4 replica reduce + softmax partials ------------
__global__ __launch_bounds__(256) void k3_soft(
    const float* __restrict__ inflb, const float* __restrict__ rep2,
    const float* __restrict__ embT, float* __restrict__ psum, int n_nodes)
{
    __shared__ float tab[4][64];
    const int tid  = threadIdx.x;
    const int lane = tid & 63;
    const int wv   = __builtin_amdgcn_readfirstlane(tid >> 6);
    const int node = blockIdx.x * 64 + lane;
    const bool ok  = (node < n_nodes);

    // phase A: reduce 128 slices of this chunk; wave wv owns 32 slices.
    // lane = s0(2b) x col4(4b): float4 per lane, 8 slice-steps.
    {
        const float* chunk = rep2 + (size_t)blockIdx.x * ROWB;
        const int s0 = lane >> 4;        // 0..3
        const int c4 = lane & 15;        // 0..15
        float4 a = make_float4(0.f, 0.f, 0.f, 0.f);
#pragma unroll
        for (int i = 0; i < 8; i++) {
            const int slice = 32 * wv + s0 + 4 * i;
            float4 v = ((const float4*)(chunk + slice * 64))[c4];
            a.x += v.x; a.y += v.y; a.z += v.z; a.w += v.w;
        }
        // reduce over s0 (lane bits 4-5) via xor butterfly
#pragma unroll
        for (int off = 16; off <= 32; off <<= 1) {
            a.x += __shfl_xor(a.x, off, 64);
            a.y += __shfl_xor(a.y, off, 64);
            a.z += __shfl_xor(a.z, off, 64);
            a.w += __shfl_xor(a.w, off, 64);
        }
        if (s0 == 0) {
            tab[wv][4 * c4 + 0] = a.x;
            tab[wv][4 * c4 + 1] = a.y;
            tab[wv][4 * c4 + 2] = a.z;
            tab[wv][4 * c4 + 3] = a.w;
        }
    }
    __syncthreads();

    // phase B: block softmax partial (wave 0)
    if (wv == 0) {
        float infl = ok ? inflb[node] + tab[0][lane] + tab[1][lane]
                          + tab[2][lane] + tab[3][lane]
                        : -1e30f;
        float m = infl;
#pragma unroll
        for (int off = 32; off; off >>= 1)
            m = fmaxf(m, __shfl_down(m, off, 64));
        m = __shfl(m, 0, 64);

        const float w = ok ? expf(infl - m) : 0.f;
        float v13[13];
        v13[0] = w;
#pragma unroll
        for (int j = 0; j < DEMB; j++)
            v13[1 + j] = ok ? w * embT[(size_t)j * n_nodes + node] : 0.f;

#pragma unroll
        for (int v = 0; v < 13; v++) {
            float x = v13[v];
#pragma unroll
            for (int off = 32; off; off >>= 1)
                x += __shfl_down(x, off, 64);
            v13[v] = x;
        }
        if (lane == 0) {
            psum[blockIdx.x * 14] = m;
#pragma unroll
            for (int v = 0; v < 13; v++)
                psum[blockIdx.x * 14 + 1 + v] = v13[v];
        }
    }
}

// ---------------- K4: merge partials + MLP head (512 thr, reg-rich) -------
__global__ __launch_bounds__(512, 1) void k4_head(
    const float* __restrict__ psum,
    const float* __restrict__ W1, const float* __restrict__ b1,
    const float* __restrict__ W2, const float* __restrict__ b2,
    const float* __restrict__ Wy, const float* __restrict__ by,
    const float* __restrict__ Wx, const float* __restrict__ bx,
    float* __restrict__ out, int nblk)
{
    const int t  = threadIdx.x;
    const int wv = t >> 6;      // 0..7
    const int ln = t & 63;

    __shared__ float sred[8][14];
    __shared__ float tot[14];
    __shared__ float g[DEMB];
    __shared__ float h1[DH];
    __shared__ float part[4][DH];
    __shared__ float h2[DH];
    __shared__ float wred[8][5];

    float m = -1e30f;
    for (int b = t; b < nblk; b += 512) m = fmaxf(m, psum[b * 14]);
#pragma unroll
    for (int off = 32; off; off >>= 1)
        m = fmaxf(m, __shfl_down(m, off, 64));
    if (ln == 0) sred[wv][0] = m;
    __syncthreads();
    float M = sred[0][0];
#pragma unroll
    for (int i = 1; i < 8; i++) M = fmaxf(M, sred[i][0]);
    __syncthreads();

    float acc[13];
#pragma unroll
    for (int v = 0; v < 13; v++) acc[v] = 0.f;
    for (int b = t; b < nblk; b += 512) {
        float sc = expf(psum[b * 14] - M);
#pragma unroll
        for (int v = 0; v < 13; v++)
            acc[v] = fmaf(sc, psum[b * 14 + 1 + v], acc[v]);
    }
#pragma unroll
    for (int v = 0; v < 13; v++) {
        float x = acc[v];
#pragma unroll
        for (int off = 32; off; off >>= 1)
            x += __shfl_down(x, off, 64);
        if (ln == 0) sred[wv][v] = x;
    }
    __syncthreads();
    if (t < 13) {
        float s = 0.f;
#pragma unroll
        for (int i = 0; i < 8; i++) s += sred[i][t];
        tot[t] = s;
    }
    __syncthreads();
    if (t < DEMB) g[t] = tot[1 + t] / tot[0];
    __syncthreads();

    if (t < DH) {
        float s1 = b1[t];
#pragma unroll
        for (int i = 0; i < DEMB; i++) s1 = fmaf(g[i], W1[i * DH + t], s1);
        h1[t] = fmaxf(s1, 0.f);
    }
    __syncthreads();

    {
        const int o  = t & 127;
        const int ks = t >> 7;           // 0..3
        float s = 0.f;
        const float* w2 = W2 + (size_t)(32 * ks) * DH + o;
#pragma unroll 8
        for (int i = 0; i < 32; i++)
            s = fmaf(h1[32 * ks + i], w2[i * DH], s);
        part[ks][o] = s;
    }
    __syncthreads();
    if (t < DH)
        h2[t] = fmaxf(b2[t] + part[0][t] + part[1][t] + part[2][t] + part[3][t], 0.f);
    __syncthreads();

    if (t < DH) {
        const float v = h2[t];
        float pr[5];
#pragma unroll
        for (int j = 0; j < 4; j++) pr[j] = v * Wx[t * 4 + j];
        pr[4] = v * Wy[t];
#pragma unroll
        for (int j = 0; j < 5; j++) {
            float x = pr[j];
#pragma unroll
            for (int off = 32; off; off >>= 1)
                x += __shfl_down(x, off, 64);
            if (ln == 0) wred[wv][j] = x;
        }
    }
    __syncthreads();
    if (t < 4)
        out[t] = (wred[0][t] + wred[1][t] + bx[t]) / 10.0f;
    else if (t == 4)
        out[4] = wred[0][4] + wred[1][4] + by[0];
}

extern "C" void kernel_launch(void* const* d_in, const int* in_sizes, int n_in,
                              void* d_out, int out_size, void* d_ws, size_t ws_size,
                              hipStream_t stream) {
    const float* nodes   = (const float*)d_in[0];
    const int*   senders = (const int*)d_in[1];
    const int*   recvs   = (const int*)d_in[2];
    const float* W_enc   = (const float*)d_in[3];
    const float* b_enc   = (const float*)d_in[4];
    const float* W_inf   = (const float*)d_in[5];
    const float* b_inf   = (const float*)d_in[6];
    const float* W_emb   = (const float*)d_in[7];
    const float* b_emb   = (const float*)d_in[8];
    const float* W1      = (const float*)d_in[9];
    const float* b1      = (const float*)d_in[10];
    const float* W2      = (const float*)d_in[11];
    const float* b2      = (const float*)d_in[12];
    const float* Wy      = (const float*)d_in[13];
    const float* by      = (const float*)d_in[14];
    const float* Wx      = (const float*)d_in[15];
    const float* bx      = (const float*)d_in[16];
    float* out = (float*)d_out;

    const int n_nodes = in_sizes[0] / NF;   // 50000
    const int n_edges = in_sizes[1];        // 1600000
    const int nb64 = (n_nodes + 63) / 64;   // 782

    // workspace layout (floats):
    float* ws    = (float*)d_ws;
    float* p     = ws;                                    // [N]
    float* inflb = ws + n_nodes;                          // [N]
    float* embT  = ws + 2 * (size_t)n_nodes;              // [12][N]
    float* rep2  = ws + 14 * (size_t)n_nodes;             // [nb64][128][64]
    float* psum  = rep2 + (size_t)nb64 * ROWB;            // [nb64*14]

    // allow 100 KB dynamic LDS for k2 (default cap is 64 KB)
    (void)hipFuncSetAttribute((const void*)k2_scatter,
                              hipFuncAttributeMaxDynamicSharedMemorySize,
                              R_SCAT * (int)sizeof(float));

    hipLaunchKernelGGL(k1_node, dim3(nb64), dim3(256), 0, stream,
                       nodes, W_enc, b_enc, W_inf, b_inf, W_emb, b_emb,
                       p, inflb, embT, n_nodes);
    hipLaunchKernelGGL(k2_scatter, dim3(NSLICE * NRANGE), dim3(1024),
                       R_SCAT * sizeof(float), stream,
                       senders, recvs, p, rep2, n_nodes, n_edges);
    hipLaunchKernelGGL(k3_soft, dim3(nb64), dim3(256), 0, stream,
                       inflb, rep2, embT, psum, n_nodes);
    hipLaunchKernelGGL(k4_head, dim3(1), dim3(512), 0, stream,
                       psum, W1, b1, W2, b2, Wy, by, Wx, bx, out, nb64);
}